// Round 23
// baseline (31.862 us; speedup 1.0000x reference)
//
#include <hip/hip_runtime.h>
#include <math.h>

#define BB 4
#define ND 256
#define NE 512
#define CC 256

#define K2E 2.8853900817779268f   // 2 * log2(e): exp2(K2E*x) = e^{2x}
#define LOG2E 1.4426950408889634f
#define LN2 0.6931471805599453f

typedef unsigned int u32;
typedef unsigned short u16;
typedef __attribute__((ext_vector_type(8))) short bf16x8;   // 8 bf16 (4 VGPR)
typedef __attribute__((ext_vector_type(4))) float f32x4;
typedef __attribute__((ext_vector_type(4))) u32   u32x4;

// pack 2 f32 -> 1 u32 of 2 bf16 (lo in [15:0], hi in [31:16])
__device__ __forceinline__ u32 cvt_pk(float lo, float hi) {
    u32 r;
    asm("v_cvt_pk_bf16_f32 %0, %1, %2" : "=v"(r) : "v"(lo), "v"(hi));
    return r;
}

// ---------------------------------------------------------------------------
// MFMA projection, LDS-staged (R22 structure — 3.7us measured).
// Only change: enc epilogue now writes Et in F32 c-quads:
//   Etf[b][cg][e] = float4{ E[4cg..4cg+3][e] }   (cg = c/4, 64 groups)
// so attn needs ZERO bf16-unpack ops (the last untouched issue-slice).
//   dec: Dexp[n][c] row-major f32 (unchanged)
// ---------------------------------------------------------------------------
__global__ __launch_bounds__(256) void proj_kernel(
    const float* __restrict__ xdec, const float* __restrict__ xenc,
    const float* __restrict__ w1,   const float* __restrict__ w2,
    float* __restrict__ Etf, float* __restrict__ Dexp)
{
    __shared__ u16  Xb[64 * 40];   // 64 rows x 32 k bf16 (+8 pad)
    __shared__ u16  Wb[32 * 40];   // 32 cols x 32 k bf16
    __shared__ float Ct[64][36];   // enc epilogue transpose staging (16B rows)

    const int row0 = blockIdx.x * 64;     // M base (0..3071)
    const int col0 = blockIdx.y * 32;     // N base (0..224)
    const bool is_enc = (row0 < BB * NE);

    const float* X  = is_enc ? xenc : xdec;
    const float* Wm = is_enc ? w1   : w2;
    const int xrow0 = is_enc ? row0 : (row0 - BB * NE);

    const int tid = threadIdx.x;
    const int xsr = tid >> 2, xsk = (tid & 3) * 8;   // X stager
    const int wsr = tid >> 3, wsk = (tid & 7) * 4;   // W stager

    const int wv = tid >> 6, l = tid & 63;
    const int lm = l & 15, kg = l >> 4;

    const float* Xp = X  + (size_t)(xrow0 + xsr) * CC + xsk;
    const float* Wp = Wm + (size_t)(col0  + wsr) * CC + wsk;

    f32x4 acc[2] = {{0.f,0.f,0.f,0.f}, {0.f,0.f,0.f,0.f}};

    float4 xv0 = *(const float4*)Xp;
    float4 xv1 = *(const float4*)(Xp + 4);
    float4 wq  = *(const float4*)Wp;

    for (int k0 = 0; k0 < CC; k0 += 32) {
        __syncthreads();
        {
            u32x4 xw = { cvt_pk(xv0.x, xv0.y), cvt_pk(xv0.z, xv0.w),
                         cvt_pk(xv1.x, xv1.y), cvt_pk(xv1.z, xv1.w) };
            *(u32x4*)&Xb[xsr * 40 + xsk] = xw;
            u32 w0 = cvt_pk(wq.x, wq.y), w1p = cvt_pk(wq.z, wq.w);
            *(u32*)&Wb[wsr * 40 + wsk]     = w0;
            *(u32*)&Wb[wsr * 40 + wsk + 2] = w1p;
        }
        __syncthreads();
        if (k0 + 32 < CC) {
            xv0 = *(const float4*)(Xp + k0 + 32);
            xv1 = *(const float4*)(Xp + k0 + 36);
            wq  = *(const float4*)(Wp + k0 + 32);
        }
        bf16x8 af  = *(const bf16x8*)&Xb[(wv * 16 + lm) * 40 + kg * 8];
        bf16x8 bf0 = *(const bf16x8*)&Wb[lm * 40 + kg * 8];
        bf16x8 bf1 = *(const bf16x8*)&Wb[(16 + lm) * 40 + kg * 8];
        acc[0] = __builtin_amdgcn_mfma_f32_16x16x32_bf16(af, bf0, acc[0], 0, 0, 0);
        acc[1] = __builtin_amdgcn_mfma_f32_16x16x32_bf16(af, bf1, acc[1], 0, 0, 0);
    }

    float ex[2][4];
#pragma unroll
    for (int j = 0; j < 2; ++j)
#pragma unroll
        for (int r = 0; r < 4; ++r)
            ex[j][r] = __builtin_amdgcn_exp2f(
                K2E * fminf(fmaxf(acc[j][r], -9.f), 9.f));

    // C/D layout [m89]: col = lane&15 (+j*16), row = kg*4 + r (+wv*16)
    if (is_enc) {
        __syncthreads();
#pragma unroll
        for (int j = 0; j < 2; ++j)
#pragma unroll
            for (int r = 0; r < 4; ++r)
                Ct[wv * 16 + kg * 4 + r][j * 16 + lm] = ex[j][r];
        __syncthreads();
        const int b  = row0 >> 9;
        const int e0 = row0 & 511;
        const int e  = tid & 63;
        const int gL = tid >> 6;            // 0..3; groups gL and gL+4
#pragma unroll
        for (int r = 0; r < 2; ++r) {
            const int g  = gL + r * 4;      // 0..7 within 32-col tile
            const int cg = (col0 >> 2) + g; // global c-quad index
            float4 val = *(const float4*)&Ct[e][g * 4];
            *(float4*)&Etf[(((size_t)b * 64 + cg) * 512 + e0 + e) * 4] = val;
        }
    } else {
        const int n = xrow0 + wv * 16 + kg * 4;
#pragma unroll
        for (int j = 0; j < 2; ++j)
#pragma unroll
            for (int r = 0; r < 4; ++r)
                Dexp[(size_t)(n + r) * CC + col0 + j * 16 + lm] = ex[j][r];
    }
}

// ---------------------------------------------------------------------------
// Fused tanh-dot + log_softmax — R17 structure, F32 E (no unpack ops).
//   p'[n,e] = -2 * sum_c v_c / (1 + E*D)    (sum(v) shift cancels)
// Per element: exactly d-fma, rcp, acc-fma. 512 thr (tid = e), 2 decoder
// rows/block, 512 blocks. E: one float4 = 4 c for this lane's e; 2-deep
// ping-pong prefetch. v/D: block-uniform float4 (scalarizable).
// ---------------------------------------------------------------------------
__global__ __launch_bounds__(512) void attn_kernel(
    const float* __restrict__ Etf, const float* __restrict__ Dexp,
    const float* __restrict__ v, float* __restrict__ out)
{
    __shared__ float prod[2][NE];

    const int blk = blockIdx.x;       // 0..511
    const int b   = blk >> 7;
    const int n0  = (blk & 127) * 2;
    const int tid = threadIdx.x;      // == e

    const float* __restrict__ D0 = Dexp + (size_t)(b * ND + n0) * CC;
    const float* __restrict__ D1 = D0 + CC;
    const float4* Ec = (const float4*)Etf + (size_t)b * 64 * 512 + tid;

    float a0 = 0.f, a1 = 0.f;

#define PROCG(E4, CG) do {                                                   \
        const int c4 = (CG) * 4;                                             \
        const float4 vq = *(const float4*)&v [c4];                           \
        const float4 q0 = *(const float4*)&D0[c4];                           \
        const float4 q1 = *(const float4*)&D1[c4];                           \
        a0 = fmaf(vq.x, __builtin_amdgcn_rcpf(fmaf(E4.x, q0.x, 1.0f)), a0);  \
        a1 = fmaf(vq.x, __builtin_amdgcn_rcpf(fmaf(E4.x, q1.x, 1.0f)), a1);  \
        a0 = fmaf(vq.y, __builtin_amdgcn_rcpf(fmaf(E4.y, q0.y, 1.0f)), a0);  \
        a1 = fmaf(vq.y, __builtin_amdgcn_rcpf(fmaf(E4.y, q1.y, 1.0f)), a1);  \
        a0 = fmaf(vq.z, __builtin_amdgcn_rcpf(fmaf(E4.z, q0.z, 1.0f)), a0);  \
        a1 = fmaf(vq.z, __builtin_amdgcn_rcpf(fmaf(E4.z, q1.z, 1.0f)), a1);  \
        a0 = fmaf(vq.w, __builtin_amdgcn_rcpf(fmaf(E4.w, q0.w, 1.0f)), a0);  \
        a1 = fmaf(vq.w, __builtin_amdgcn_rcpf(fmaf(E4.w, q1.w, 1.0f)), a1);  \
    } while (0)

    float4 e4a = Ec[0], e4b;
    for (int cg = 0; cg < 64; cg += 2) {
        e4b = Ec[(size_t)(cg + 1) * 512];
        PROCG(e4a, cg);
        if (cg + 2 < 64) e4a = Ec[(size_t)(cg + 2) * 512];
        PROCG(e4b, cg + 1);
    }
#undef PROCG

    prod[0][tid] = -2.0f * a0;
    prod[1][tid] = -2.0f * a1;
    __syncthreads();

    // log_softmax: wave w (w<2) handles decoder row n0+w
    const int w    = tid >> 6;
    const int lane = tid & 63;
    if (w < 2) {
        float p[8];
#pragma unroll
        for (int i = 0; i < 8; ++i) p[i] = prod[w][lane + 64 * i];
        float m = p[0];
#pragma unroll
        for (int i = 1; i < 8; ++i) m = fmaxf(m, p[i]);
#pragma unroll
        for (int off = 1; off < 64; off <<= 1) m = fmaxf(m, __shfl_xor(m, off));
        float s = 0.f;
#pragma unroll
        for (int i = 0; i < 8; ++i) s += __builtin_amdgcn_exp2f((p[i] - m) * LOG2E);
#pragma unroll
        for (int off = 1; off < 64; off <<= 1) s += __shfl_xor(s, off);
        const float lse = m + __builtin_amdgcn_logf(s) * LN2;

        float* o = out + (size_t)(b * ND + n0 + w) * NE;
#pragma unroll
        for (int i = 0; i < 8; ++i) o[lane + 64 * i] = p[i] - lse;
    }
}

// ---------------------------------------------------------------------------
extern "C" void kernel_launch(void* const* d_in, const int* in_sizes, int n_in,
                              void* d_out, int out_size, void* d_ws, size_t ws_size,
                              hipStream_t stream) {
    const float* xdec = (const float*)d_in[0];   // (4,256,256)
    const float* xenc = (const float*)d_in[1];   // (4,512,256)
    const float* w1   = (const float*)d_in[2];   // (256,256)
    const float* w2   = (const float*)d_in[3];   // (256,256)
    const float* v    = (const float*)d_in[4];   // (1,256)
    float* out = (float*)d_out;                  // (4,256,512)

    char* ws = (char*)d_ws;
    float* Etf  = (float*)ws;                    // [4][64][512] float4 = 2 MB
    float* Dexp = (float*)(ws + (2u << 20));     // [1024][256] f32 = 1 MB

    dim3 gproj(48, 8);                           // 3072/64 rows, 256/32 cols
    proj_kernel<<<gproj, 256, 0, stream>>>(xdec, xenc, w1, w2, Etf, Dexp);
    attn_kernel<<<(BB * ND) / 2, 512, 0, stream>>>(Etf, Dexp, v, out);
}

// Round 24
// 26.555 us; speedup vs baseline: 1.1999x; 1.1999x over previous
//
#include <hip/hip_runtime.h>
#include <math.h>

#define BB 4
#define ND 256
#define NE 512
#define CC 256

#define K2E 2.8853900817779268f   // 2 * log2(e): exp2(K2E*x) = e^{2x}
#define LOG2E 1.4426950408889634f
#define LN2 0.6931471805599453f

typedef unsigned int u32;
typedef unsigned short u16;
typedef __attribute__((ext_vector_type(8))) short bf16x8;   // 8 bf16 (4 VGPR)
typedef __attribute__((ext_vector_type(4))) float f32x4;
typedef __attribute__((ext_vector_type(4))) u32   u32x4;

__device__ __forceinline__ float bflo(u32 u) { return __builtin_bit_cast(float, u << 16); }
__device__ __forceinline__ float bfhi(u32 u) { return __builtin_bit_cast(float, u & 0xffff0000u); }

// pack 2 f32 -> 1 u32 of 2 bf16 (lo in [15:0], hi in [31:16])
__device__ __forceinline__ u32 cvt_pk(float lo, float hi) {
    u32 r;
    asm("v_cvt_pk_bf16_f32 %0, %1, %2" : "=v"(r) : "v"(lo), "v"(hi));
    return r;
}

// ---------------------------------------------------------------------------
// MFMA projection, LDS-staged (classic §5): coalesced f32 loads -> cvt once
// -> bf16 LDS tiles -> ds_read_b128 fragments -> 16x16x32 MFMA.
// Tile: 64 M x 32 N, K-step 32; grid (48,8) = 384 blocks, 256 thr (4 waves).
// Measured 3.7us (R22 = best). R23's f32-E variant regressed; reverted.
//   enc: Et4[b][cq][e] = uint4 of 4 bf16-c-pair words (8 c per 16B)
//   dec: Dexp[n][c] row-major f32
// ---------------------------------------------------------------------------
__global__ __launch_bounds__(256) void proj_kernel(
    const float* __restrict__ xdec, const float* __restrict__ xenc,
    const float* __restrict__ w1,   const float* __restrict__ w2,
    uint4* __restrict__ Et4, float* __restrict__ Dexp)
{
    __shared__ u16  Xb[64 * 40];   // 64 rows x 32 k bf16 (+8 pad)
    __shared__ u16  Wb[32 * 40];   // 32 cols x 32 k bf16
    __shared__ float Ct[64][33];   // enc epilogue transpose staging

    const int row0 = blockIdx.x * 64;     // M base (0..3071)
    const int col0 = blockIdx.y * 32;     // N base (0..224)
    const bool is_enc = (row0 < BB * NE);

    const float* X  = is_enc ? xenc : xdec;
    const float* Wm = is_enc ? w1   : w2;
    const int xrow0 = is_enc ? row0 : (row0 - BB * NE);

    const int tid = threadIdx.x;
    const int xsr = tid >> 2, xsk = (tid & 3) * 8;   // X stager
    const int wsr = tid >> 3, wsk = (tid & 7) * 4;   // W stager

    const int wv = tid >> 6, l = tid & 63;
    const int lm = l & 15, kg = l >> 4;

    const float* Xp = X  + (size_t)(xrow0 + xsr) * CC + xsk;
    const float* Wp = Wm + (size_t)(col0  + wsr) * CC + wsk;

    f32x4 acc[2] = {{0.f,0.f,0.f,0.f}, {0.f,0.f,0.f,0.f}};

    float4 xv0 = *(const float4*)Xp;
    float4 xv1 = *(const float4*)(Xp + 4);
    float4 wq  = *(const float4*)Wp;

    for (int k0 = 0; k0 < CC; k0 += 32) {
        __syncthreads();   // LDS free (prev step's reads done)
        {
            u32x4 xw = { cvt_pk(xv0.x, xv0.y), cvt_pk(xv0.z, xv0.w),
                         cvt_pk(xv1.x, xv1.y), cvt_pk(xv1.z, xv1.w) };
            *(u32x4*)&Xb[xsr * 40 + xsk] = xw;            // 16B aligned
            u32 w0 = cvt_pk(wq.x, wq.y), w1p = cvt_pk(wq.z, wq.w);
            *(u32*)&Wb[wsr * 40 + wsk]     = w0;          // 4B  aligned
            *(u32*)&Wb[wsr * 40 + wsk + 2] = w1p;
        }
        __syncthreads();
        if (k0 + 32 < CC) {                               // prefetch next
            xv0 = *(const float4*)(Xp + k0 + 32);
            xv1 = *(const float4*)(Xp + k0 + 36);
            wq  = *(const float4*)(Wp + k0 + 32);
        }
        bf16x8 af  = *(const bf16x8*)&Xb[(wv * 16 + lm) * 40 + kg * 8];
        bf16x8 bf0 = *(const bf16x8*)&Wb[lm * 40 + kg * 8];
        bf16x8 bf1 = *(const bf16x8*)&Wb[(16 + lm) * 40 + kg * 8];
        acc[0] = __builtin_amdgcn_mfma_f32_16x16x32_bf16(af, bf0, acc[0], 0, 0, 0);
        acc[1] = __builtin_amdgcn_mfma_f32_16x16x32_bf16(af, bf1, acc[1], 0, 0, 0);
    }

    float ex[2][4];
#pragma unroll
    for (int j = 0; j < 2; ++j)
#pragma unroll
        for (int r = 0; r < 4; ++r)
            ex[j][r] = __builtin_amdgcn_exp2f(
                K2E * fminf(fmaxf(acc[j][r], -9.f), 9.f));

    // C/D layout [m89]: col = lane&15 (+j*16), row = kg*4 + r (+wv*16)
    if (is_enc) {
        __syncthreads();
#pragma unroll
        for (int j = 0; j < 2; ++j)
#pragma unroll
            for (int r = 0; r < 4; ++r)
                Ct[wv * 16 + kg * 4 + r][j * 16 + lm] = ex[j][r];
        __syncthreads();
        const int b  = row0 >> 9;
        const int e0 = row0 & 511;
        const int e  = tid & 63;
        const int cqL = tid >> 6;          // 0..3 (32 cols = 4 cq)
        const float* cr = &Ct[e][cqL * 8];
        u32x4 q = { cvt_pk(cr[0], cr[1]), cvt_pk(cr[2], cr[3]),
                    cvt_pk(cr[4], cr[5]), cvt_pk(cr[6], cr[7]) };
        Et4[((size_t)b * 32 + (col0 >> 3) + cqL) * 512 + e0 + e] =
            __builtin_bit_cast(uint4, q);
    } else {
        const int n = xrow0 + wv * 16 + kg * 4;
#pragma unroll
        for (int j = 0; j < 2; ++j)
#pragma unroll
            for (int r = 0; r < 4; ++r)
                Dexp[(size_t)(n + r) * CC + col0 + j * 16 + lm] = ex[j][r];
    }
}

// ---------------------------------------------------------------------------
// Fused tanh-dot + log_softmax — R12/R17 structure (best measured; at its
// issue floor per R21 counters and five falsified alternatives).
//   p'[n,e] = -2 * sum_c v_c / (1 + E*D)    (sum(v) shift cancels)
//   v0/d0 + v1/d1 = (v0*d1 + v1*d0) / (d0*d1),  d = fma(E, D, 1)
// 512 thr (tid = e), 2 decoder rows/block, 512 blocks.
// ---------------------------------------------------------------------------
__global__ __launch_bounds__(512) void attn_kernel(
    const uint4* __restrict__ Et4, const float* __restrict__ Dexp,
    const float* __restrict__ v, float* __restrict__ out)
{
    __shared__ float prod[2][NE];

    const int blk = blockIdx.x;       // 0..511
    const int b   = blk >> 7;
    const int n0  = (blk & 127) * 2;
    const int tid = threadIdx.x;      // == e

    const float* __restrict__ D0 = Dexp + (size_t)(b * ND + n0) * CC;
    const float* __restrict__ D1 = D0 + CC;
    const uint4* Ec = Et4 + (size_t)b * 32 * 512 + tid;

    float a0 = 0.f, a1 = 0.f;

#define PAIR(ACC, E0, E1, V0, V1, Dx0, Dx1) do {                             \
        const float _d0 = fmaf((E0), (Dx0), 1.0f);                           \
        const float _d1 = fmaf((E1), (Dx1), 1.0f);                           \
        const float _num = fmaf((V1), _d0, (V0) * _d1);                      \
        ACC = fmaf(_num, __builtin_amdgcn_rcpf(_d0 * _d1), ACC);             \
    } while (0)

#define PROC(E4, CQ) do {                                                    \
        const int c8 = (CQ) * 8;                                             \
        const float4 vA  = *(const float4*)&v [c8];                          \
        const float4 vB  = *(const float4*)&v [c8 + 4];                      \
        const float4 dA0 = *(const float4*)&D0[c8];                          \
        const float4 dB0 = *(const float4*)&D0[c8 + 4];                      \
        const float4 dA1 = *(const float4*)&D1[c8];                          \
        const float4 dB1 = *(const float4*)&D1[c8 + 4];                      \
        PAIR(a0, bflo(E4.x), bfhi(E4.x), vA.x, vA.y, dA0.x, dA0.y);          \
        PAIR(a1, bflo(E4.x), bfhi(E4.x), vA.x, vA.y, dA1.x, dA1.y);          \
        PAIR(a0, bflo(E4.y), bfhi(E4.y), vA.z, vA.w, dA0.z, dA0.w);          \
        PAIR(a1, bflo(E4.y), bfhi(E4.y), vA.z, vA.w, dA1.z, dA1.w);          \
        PAIR(a0, bflo(E4.z), bfhi(E4.z), vB.x, vB.y, dB0.x, dB0.y);          \
        PAIR(a1, bflo(E4.z), bfhi(E4.z), vB.x, vB.y, dB1.x, dB1.y);          \
        PAIR(a0, bflo(E4.w), bfhi(E4.w), vB.z, vB.w, dB0.z, dB0.w);          \
        PAIR(a1, bflo(E4.w), bfhi(E4.w), vB.z, vB.w, dB1.z, dB1.w);          \
    } while (0)

    uint4 e4a = Ec[0], e4b;
    for (int cq = 0; cq < 32; cq += 2) {
        e4b = Ec[(size_t)(cq + 1) * 512];
        PROC(e4a, cq);
        if (cq + 2 < 32) e4a = Ec[(size_t)(cq + 2) * 512];
        PROC(e4b, cq + 1);
    }
#undef PROC
#undef PAIR

    prod[0][tid] = -2.0f * a0;
    prod[1][tid] = -2.0f * a1;
    __syncthreads();

    // log_softmax: wave w (w<2) handles decoder row n0+w
    const int w    = tid >> 6;
    const int lane = tid & 63;
    if (w < 2) {
        float p[8];
#pragma unroll
        for (int i = 0; i < 8; ++i) p[i] = prod[w][lane + 64 * i];
        float m = p[0];
#pragma unroll
        for (int i = 1; i < 8; ++i) m = fmaxf(m, p[i]);
#pragma unroll
        for (int off = 1; off < 64; off <<= 1) m = fmaxf(m, __shfl_xor(m, off));
        float s = 0.f;
#pragma unroll
        for (int i = 0; i < 8; ++i) s += __builtin_amdgcn_exp2f((p[i] - m) * LOG2E);
#pragma unroll
        for (int off = 1; off < 64; off <<= 1) s += __shfl_xor(s, off);
        const float lse = m + __builtin_amdgcn_logf(s) * LN2;

        float* o = out + (size_t)(b * ND + n0 + w) * NE;
#pragma unroll
        for (int i = 0; i < 8; ++i) o[lane + 64 * i] = p[i] - lse;
    }
}

// ---------------------------------------------------------------------------
extern "C" void kernel_launch(void* const* d_in, const int* in_sizes, int n_in,
                              void* d_out, int out_size, void* d_ws, size_t ws_size,
                              hipStream_t stream) {
    const float* xdec = (const float*)d_in[0];   // (4,256,256)
    const float* xenc = (const float*)d_in[1];   // (4,512,256)
    const float* w1   = (const float*)d_in[2];   // (256,256)
    const float* w2   = (const float*)d_in[3];   // (256,256)
    const float* v    = (const float*)d_in[4];   // (1,256)
    float* out = (float*)d_out;                  // (4,256,512)

    char* ws = (char*)d_ws;
    uint4* Et4  = (uint4*)ws;                    // [4][32][512] uint4 = 1 MB
    float* Dexp = (float*)(ws + (1u << 20));     // [1024][256] f32 = 1 MB

    dim3 gproj(48, 8);                           // 3072/64 rows, 256/32 cols
    proj_kernel<<<gproj, 256, 0, stream>>>(xdec, xenc, w1, w2, Et4, Dexp);
    attn_kernel<<<(BB * ND) / 2, 512, 0, stream>>>(Et4, Dexp, v, out);
}